// Round 15
// baseline (156.206 us; speedup 1.0000x reference)
//
#include <hip/hip_runtime.h>

#define NN 4681        // total nodes
#define NI 585         // internal (parent) nodes
#define KP 320         // K padded to multiple of 32

typedef __bf16 bf16x8 __attribute__((ext_vector_type(8)));
typedef float f32x4 __attribute__((ext_vector_type(4)));
typedef unsigned short u16x4 __attribute__((ext_vector_type(4)));

__device__ __forceinline__ float sigm(float x) { return 1.f / (1.f + expf(-x)); }

__device__ __forceinline__ unsigned short f2bf(float x) {
  unsigned u = __float_as_uint(x);
  u += 0x7FFFu + ((u >> 16) & 1u);
  return (unsigned short)(u >> 16);
}

__device__ __forceinline__ bf16x8 mk_frag(const unsigned short* lo, const unsigned short* hi) {
  union { u16x4 p[2]; bf16x8 v; } t;
  t.p[0] = *(const u16x4*)lo;
  t.p[1] = *(const u16x4*)hi;
  return t.v;
}

// ---------------- prep: bf16 weight transposes (K padded to 320 with zeros) ----------------
// bid: [0,1200) WT; [1200,1500) WfhT; [1500,2400) WiouhT; [2400,2656) h_bf pad; [2656,2693) hsb_bf pad
__global__ __launch_bounds__(256) void prep_kernel(
    const float* __restrict__ W_ioux, const float* __restrict__ W_fx,
    const float* __restrict__ W_fh, const float* __restrict__ W_iouh,
    unsigned short* __restrict__ WT, unsigned short* __restrict__ WfhT,
    unsigned short* __restrict__ WiouhT,
    unsigned short* __restrict__ h_bf, unsigned short* __restrict__ hsb_bf)
{
  const int bid = blockIdx.x, tid = threadIdx.x;
  if (bid < 1200) {
    const int c = bid;
    for (int k = tid; k < KP; k += 256) {
      float v = 0.f;
      if (k < 300) v = (c < 900) ? W_ioux[(size_t)k * 900 + c] : W_fx[(size_t)k * 300 + (c - 900)];
      WT[(size_t)c * KP + k] = f2bf(v);
    }
  } else if (bid < 1500) {
    const int c = bid - 1200;
    for (int k = tid; k < KP; k += 256) {
      float v = (k < 300) ? W_fh[(size_t)k * 300 + c] : 0.f;
      WfhT[(size_t)c * KP + k] = f2bf(v);
    }
  } else if (bid < 2400) {
    const int c = bid - 1500;
    for (int k = tid; k < KP; k += 256) {
      float v = (k < 300) ? W_iouh[(size_t)k * 900 + c] : 0.f;
      WiouhT[(size_t)c * KP + k] = f2bf(v);
    }
  } else if (bid < 2656) {
    const int r0 = (bid - 2400) * 16;
    for (int idx = tid; idx < 320; idx += 256) {
      const int r = r0 + idx / 20, k = 300 + idx % 20;
      h_bf[(size_t)r * KP + k] = 0;
    }
  } else {
    const int r0 = (bid - 2656) * 16;
    for (int idx = tid; idx < 320; idx += 256) {
      const int r = r0 + idx / 20, k = 300 + idx % 20;
      if (r < NI) hsb_bf[(size_t)r * KP + k] = 0;
    }
  }
}

// ---------------- MFMA X-GEMM: internal -> xiou+fxo; leaf -> gates+c/h+hsb ----------------
// A staged from embed (gather) with on-the-fly f32->bf16.
__global__ __launch_bounds__(256) void fx_mfma(
    const int* __restrict__ tokens, const float* __restrict__ embed,
    const unsigned short* __restrict__ WT,
    const float* __restrict__ b_ioux, const float* __restrict__ b_fx,
    const float* __restrict__ b_iouh,
    float* __restrict__ xiou, float* __restrict__ fxo,
    float* __restrict__ c_cur, unsigned short* __restrict__ h_bf,
    float* __restrict__ hsb, unsigned short* __restrict__ hsb_bf)
{
  __shared__ unsigned short As[64][48];
  __shared__ unsigned short Bs[4][16][48];
  __shared__ int toks[64];
  const int tid = threadIdx.x;
  const int rt = blockIdx.x / 19, jt = blockIdx.x % 19;
  const bool leaf = (rt >= 10);
  const int R0 = leaf ? (585 + (rt - 10) * 64) : rt * 64;
  const int j0 = jt * 16;
  const int w = tid >> 6, lane = tid & 63, q = lane >> 4, cl = lane & 15;
  const int srow = tid >> 2, sk = (tid & 3) * 8;
  const int bp = tid >> 6, bcol = (tid >> 2) & 15;

  if (tid < 64) toks[tid] = tokens[R0 + tid];

  f32x4 acc[4] = {{0,0,0,0},{0,0,0,0},{0,0,0,0},{0,0,0,0}};
  for (int kt = 0; kt < 10; ++kt) {
    const int k0 = kt * 32;
    __syncthreads();
    {
      const float* src = embed + (size_t)toks[srow] * 300;
      const int kb = k0 + sk;
      unsigned short tmp[8];
      if (kb + 7 < 300) {
        float4 v0 = *(const float4*)(src + kb);
        float4 v1 = *(const float4*)(src + kb + 4);
        tmp[0]=f2bf(v0.x); tmp[1]=f2bf(v0.y); tmp[2]=f2bf(v0.z); tmp[3]=f2bf(v0.w);
        tmp[4]=f2bf(v1.x); tmp[5]=f2bf(v1.y); tmp[6]=f2bf(v1.z); tmp[7]=f2bf(v1.w);
      } else {
#pragma unroll
        for (int e = 0; e < 8; ++e) tmp[e] = f2bf((kb + e < 300) ? src[kb + e] : 0.f);
      }
      *(u16x4*)&As[srow][sk]     = *(u16x4*)&tmp[0];
      *(u16x4*)&As[srow][sk + 4] = *(u16x4*)&tmp[4];
    }
    {
      uint4 wv = {0, 0, 0, 0};
      const int cg = j0 + bcol;
      if (cg < 300 && (bp < 3 || !leaf))
        wv = *(const uint4*)(WT + (size_t)(bp * 300 + cg) * KP + k0 + sk);
      *(uint4*)&Bs[bp][bcol][sk] = wv;
    }
    __syncthreads();
    bf16x8 af = mk_frag(&As[16 * w + cl][4 * q], &As[16 * w + cl][16 + 4 * q]);
#pragma unroll
    for (int p = 0; p < 4; ++p) {
      if (!(p == 3 && leaf)) {
        bf16x8 bf = mk_frag(&Bs[p][cl][4 * q], &Bs[p][cl][16 + 4 * q]);
        acc[p] = __builtin_amdgcn_mfma_f32_16x16x32_bf16(af, bf, acc[p], 0, 0, 0);
      }
    }
  }

  const int jj = j0 + cl;
  if (jj >= 300) return;
  if (leaf) {
    const float bi = b_ioux[jj] + b_iouh[jj];
    const float bo = b_ioux[300 + jj] + b_iouh[300 + jj];
    const float bu = b_ioux[600 + jj] + b_iouh[600 + jj];
    float hsum = 0.f;
#pragma unroll
    for (int r = 0; r < 4; ++r) {
      const int rel = (R0 - 585) + 16 * w + 4 * q + r;
      float iv = acc[0][r] + bi, ov = acc[1][r] + bo, uv = acc[2][r] + bu;
      float cv = sigm(iv) * tanhf(uv);
      float hv = sigm(ov) * tanhf(cv);
      c_cur[(size_t)rel * 300 + jj] = cv;
      h_bf[(size_t)rel * KP + jj] = f2bf(hv);
      hsum += hv;
    }
    float tot = hsum + __shfl_xor(hsum, 16);
    if ((q & 1) == 0) {
      const int p = 73 + ((R0 - 585 + 16 * w) >> 3) + (q >> 1);
      hsb[(size_t)p * 300 + jj] = tot;
      hsb_bf[(size_t)p * KP + jj] = f2bf(tot);
    }
  } else {
#pragma unroll
    for (int r = 0; r < 4; ++r) {
      const int grow = R0 + 16 * w + 4 * q + r;
      if (grow < NI) {
        xiou[(size_t)grow * 900 + jj]       = acc[0][r] + b_ioux[jj];
        xiou[(size_t)grow * 900 + 300 + jj] = acc[1][r] + b_ioux[300 + jj];
        xiou[(size_t)grow * 900 + 600 + jj] = acc[2][r] + b_ioux[600 + jj];
        fxo[(size_t)grow * 300 + jj]        = acc[3][r] + b_fx[jj];
      }
    }
  }
}

// ---------------- MFMA iou-GEMM + gates + h-sum for internal levels ----------------
__global__ __launch_bounds__(256) void ig_mfma(
    int M, int start, int pstart,
    const unsigned short* __restrict__ hsb_bf_in, const unsigned short* __restrict__ WiouhT,
    const float* __restrict__ xiou, const float* __restrict__ b_iouh,
    const float* __restrict__ fcb_in,
    float* __restrict__ c_cur, unsigned short* __restrict__ h_bf,
    float* __restrict__ hsb, unsigned short* __restrict__ hsb_bf_out)
{
  __shared__ unsigned short As[64][48];
  __shared__ unsigned short Bs[3][16][48];
  const int tid = threadIdx.x;
  const int rt = blockIdx.x / 19, jt = blockIdx.x % 19;
  const int R0 = rt * 64;
  const int j0 = jt * 16;
  const int w = tid >> 6, lane = tid & 63, q = lane >> 4, cl = lane & 15;
  const int srow = tid >> 2, sk = (tid & 3) * 8;
  const int bp = tid >> 6, bcol = (tid >> 2) & 15;

  f32x4 acc[3] = {{0,0,0,0},{0,0,0,0},{0,0,0,0}};
  for (int kt = 0; kt < 10; ++kt) {
    const int k0 = kt * 32;
    __syncthreads();
    *(uint4*)&As[srow][sk] = *(const uint4*)(hsb_bf_in + (size_t)(start + R0 + srow) * KP + k0 + sk);
    if (bp < 3) {
      uint4 wv = {0, 0, 0, 0};
      const int cg = j0 + bcol;
      if (cg < 300) wv = *(const uint4*)(WiouhT + (size_t)(bp * 300 + cg) * KP + k0 + sk);
      *(uint4*)&Bs[bp][bcol][sk] = wv;
    }
    __syncthreads();
    bf16x8 af = mk_frag(&As[16 * w + cl][4 * q], &As[16 * w + cl][16 + 4 * q]);
#pragma unroll
    for (int p = 0; p < 3; ++p) {
      bf16x8 bf = mk_frag(&Bs[p][cl][4 * q], &Bs[p][cl][16 + 4 * q]);
      acc[p] = __builtin_amdgcn_mfma_f32_16x16x32_bf16(af, bf, acc[p], 0, 0, 0);
    }
  }

  const int jj = j0 + cl;
  if (jj >= 300) return;
  float hsum = 0.f;
#pragma unroll
  for (int r = 0; r < 4; ++r) {
    const int rel = R0 + 16 * w + 4 * q + r;
    if (rel < M) {
      const int node = start + rel;
      float iv = acc[0][r] + xiou[(size_t)node * 900 + jj]       + b_iouh[jj];
      float ov = acc[1][r] + xiou[(size_t)node * 900 + 300 + jj] + b_iouh[300 + jj];
      float uv = acc[2][r] + xiou[(size_t)node * 900 + 600 + jj] + b_iouh[600 + jj];
      float cv = sigm(iv) * tanhf(uv) + fcb_in[(size_t)node * 300 + jj];
      float hv = sigm(ov) * tanhf(cv);
      c_cur[(size_t)rel * 300 + jj] = cv;
      h_bf[(size_t)rel * KP + jj] = f2bf(hv);
      hsum += hv;
    }
  }
  float tot = hsum + __shfl_xor(hsum, 16);
  if ((q & 1) == 0 && (R0 + 16 * w + (q >> 1) * 8) < M) {
    const int p = pstart + ((R0 + 16 * w) >> 3) + (q >> 1);
    hsb[(size_t)p * 300 + jj] = tot;
    hsb_bf_out[(size_t)p * KP + jj] = f2bf(tot);
  }
}

// ---------------- MFMA W_fh GEMM + fused f-gate + fc reduction ----------------
__global__ __launch_bounds__(256) void fcb_mfma(
    int M, int pstart,
    const unsigned short* __restrict__ h_bf, const unsigned short* __restrict__ WfhT,
    const float* __restrict__ c_cur, const float* __restrict__ b_fh,
    const float* __restrict__ fxo, float* __restrict__ fcb)
{
  __shared__ unsigned short As[64][48];
  __shared__ unsigned short Bs[16][48];
  const int tid = threadIdx.x;
  const int rt = blockIdx.x / 19, jt = blockIdx.x % 19;
  const int R0 = rt * 64;
  const int j0 = jt * 16;
  const int w = tid >> 6, lane = tid & 63, q = lane >> 4, cl = lane & 15;
  const int srow = tid >> 2, sk = (tid & 3) * 8;

  f32x4 acc = {0, 0, 0, 0};
  for (int kt = 0; kt < 10; ++kt) {
    const int k0 = kt * 32;
    __syncthreads();
    *(uint4*)&As[srow][sk] = *(const uint4*)(h_bf + (size_t)(R0 + srow) * KP + k0 + sk);
    if (tid < 64) {
      const int col = tid >> 2, ks = (tid & 3) * 8;
      uint4 wv = {0, 0, 0, 0};
      const int cg = j0 + col;
      if (cg < 300) wv = *(const uint4*)(WfhT + (size_t)cg * KP + k0 + ks);
      *(uint4*)&Bs[col][ks] = wv;
    }
    __syncthreads();
    bf16x8 af = mk_frag(&As[16 * w + cl][4 * q], &As[16 * w + cl][16 + 4 * q]);
    bf16x8 bf = mk_frag(&Bs[cl][4 * q], &Bs[cl][16 + 4 * q]);
    acc = __builtin_amdgcn_mfma_f32_16x16x32_bf16(af, bf, acc, 0, 0, 0);
  }

  const int jj = j0 + cl;
  if (jj >= 300) return;
  const int p = pstart + ((R0 + 16 * w) >> 3) + (q >> 1);
  float fc = 0.f;
#pragma unroll
  for (int r = 0; r < 4; ++r) {
    const int rel = R0 + 16 * w + 4 * q + r;
    if (rel < M) {
      const float add = b_fh[jj] + fxo[(size_t)p * 300 + jj];
      float f = sigm(acc[r] + add);
      fc += f * c_cur[(size_t)rel * 300 + jj];
    }
  }
  float tot = fc + __shfl_xor(fc, 16);
  if ((q & 1) == 0 && (R0 + 16 * w + (q >> 1) * 8) < M)
    fcb[(size_t)p * 300 + jj] = tot;
}

// ---------------- root: gates + W_lin head (1 block) ----------------
__global__ __launch_bounds__(1024) void root_kernel(
    const float* __restrict__ xiou,
    const float* __restrict__ W_iouh, const float* __restrict__ b_iouh,
    const float* __restrict__ hsb, const float* __restrict__ fcb,
    const float* __restrict__ W_lin, const float* __restrict__ b_lin,
    float* __restrict__ out)
{
  __shared__ float hs[300];
  __shared__ float siou[900];
  __shared__ float sc[300];
  const int tid = threadIdx.x;
  if (tid < 300) hs[tid] = hsb[tid];
  __syncthreads();
  if (tid < 900) {
    float acc = xiou[tid] + b_iouh[tid];
#pragma unroll 4
    for (int k = 0; k < 300; ++k) acc += hs[k] * W_iouh[(size_t)k * 900 + tid];
    siou[tid] = acc;
  }
  __syncthreads();
  if (tid < 300) {
    float cv = sigm(siou[tid]) * tanhf(siou[600 + tid]) + fcb[tid];
    float hv = sigm(siou[300 + tid]) * tanhf(cv);
    sc[tid] = cv;
    out[42 + tid] = hv;
  }
  __syncthreads();
  if (tid < 42) {
    float acc = b_lin[tid];
#pragma unroll 4
    for (int k = 0; k < 300; ++k) acc += sc[k] * W_lin[(size_t)k * 42 + tid];
    out[tid] = acc;
  }
}

extern "C" void kernel_launch(void* const* d_in, const int* in_sizes, int n_in,
                              void* d_out, int out_size, void* d_ws, size_t ws_size,
                              hipStream_t stream) {
  const int* tokens   = (const int*)d_in[0];
  const float* embed  = (const float*)d_in[3];
  const float* W_ioux = (const float*)d_in[4];
  const float* b_ioux = (const float*)d_in[5];
  const float* W_iouh = (const float*)d_in[6];
  const float* b_iouh = (const float*)d_in[7];
  const float* W_fx   = (const float*)d_in[8];
  const float* b_fx   = (const float*)d_in[9];
  const float* W_fh   = (const float*)d_in[10];
  const float* b_fh   = (const float*)d_in[11];
  const float* W_lin  = (const float*)d_in[12];
  const float* b_lin  = (const float*)d_in[13];
  float* out = (float*)d_out;

  float* ws    = (float*)d_ws;
  float* xiou  = ws;                                 // 585*900
  float* fxo   = xiou  + (size_t)NI * 900;           // 585*300
  float* hsb   = fxo   + (size_t)NI * 300;           // 585*300
  float* fcb   = hsb   + (size_t)NI * 300;           // 585*300
  float* c_cur = fcb   + (size_t)NI * 300;           // 4096*300
  unsigned short* h_bf   = (unsigned short*)(c_cur + (size_t)4096 * 300);  // 4096*320
  unsigned short* WT     = h_bf   + (size_t)4096 * KP;   // 1200*320
  unsigned short* WfhT   = WT     + (size_t)1200 * KP;   // 300*320
  unsigned short* WiouhT = WfhT   + (size_t)300 * KP;    // 900*320
  unsigned short* hsb_bf = WiouhT + (size_t)900 * KP;    // 585*320

  // P: bf16 weight transposes + pads
  prep_kernel<<<2693, 256, 0, stream>>>(W_ioux, W_fx, W_fh, W_iouh,
      WT, WfhT, WiouhT, h_bf, hsb_bf);
  // K0: MFMA X-GEMM (gather+convert inline; internal xiou/fxo + leaf gates/c/h/hsb)
  fx_mfma<<<74 * 19, 256, 0, stream>>>(tokens, embed, WT, b_ioux, b_fx, b_iouh,
      xiou, fxo, c_cur, h_bf, hsb, hsb_bf);
  // K1: fcb leaf (4096 children -> parents 73..584)
  fcb_mfma<<<64 * 19, 256, 0, stream>>>(4096, 73, h_bf, WfhT, c_cur, b_fh, fxo, fcb);
  // K2: ig 512 (nodes 73..584 -> parents 9..72)
  ig_mfma<<<8 * 19, 256, 0, stream>>>(512, 73, 9, hsb_bf, WiouhT, xiou, b_iouh, fcb,
      c_cur, h_bf, hsb, hsb_bf);
  // K3: fcb 512
  fcb_mfma<<<8 * 19, 256, 0, stream>>>(512, 9, h_bf, WfhT, c_cur, b_fh, fxo, fcb);
  // K4: ig 64 (nodes 9..72 -> parents 1..8)
  ig_mfma<<<19, 256, 0, stream>>>(64, 9, 1, hsb_bf, WiouhT, xiou, b_iouh, fcb,
      c_cur, h_bf, hsb, hsb_bf);
  // K5: fcb 64
  fcb_mfma<<<19, 256, 0, stream>>>(64, 1, h_bf, WfhT, c_cur, b_fh, fxo, fcb);
  // K6: ig 8 (nodes 1..8 -> root)
  ig_mfma<<<19, 256, 0, stream>>>(8, 1, 0, hsb_bf, WiouhT, xiou, b_iouh, fcb,
      c_cur, h_bf, hsb, hsb_bf);
  // K7: fcb 8 (root)
  fcb_mfma<<<19, 256, 0, stream>>>(8, 0, h_bf, WfhT, c_cur, b_fh, fxo, fcb);
  // K8: root
  root_kernel<<<1, 1024, 0, stream>>>(xiou, W_iouh, b_iouh, hsb, fcb, W_lin, b_lin, out);
}